// Round 21
// baseline (296.084 us; speedup 1.0000x reference)
//
#include <hip/hip_runtime.h>
#include <math.h>

#define E_EDGES 320000
#define N_NODES 10000
#define CAP 128   // bucket capacity per node (Poisson(32), max deg ~60)

typedef __attribute__((ext_vector_type(4))) float f32x4;
typedef __attribute__((ext_vector_type(8))) short s16x8;

__device__ __forceinline__ float silu_f(float v) {
  return v * __builtin_amdgcn_rcpf(1.f + __expf(-v));
}

__device__ __forceinline__ void atomAddF(float* p, float v) {
  __hip_atomic_fetch_add(p, v, __ATOMIC_RELAXED, __HIP_MEMORY_SCOPE_AGENT);
}

__device__ __forceinline__ unsigned short f2b(float x) {
  __bf16 h = (__bf16)x;
  return __builtin_bit_cast(unsigned short, h);
}
__device__ __forceinline__ float b2f(unsigned short h) {
  return __uint_as_float(((unsigned)h) << 16);
}
__device__ __forceinline__ uint2 pack4(float a, float b, float c, float d) {
  uint2 p;
  p.x = (unsigned)f2b(a) | ((unsigned)f2b(b) << 16);
  p.y = (unsigned)f2b(c) | ((unsigned)f2b(d) << 16);
  return p;
}

union U16x8 { uint4 u; s16x8 s; };
__device__ __forceinline__ s16x8 ld_frag(const unsigned short* p) {
  U16x8 x; x.u = *(const uint4*)p; return x.s;
}

// ---- MFMA dense layer, swapped operands (D[feature][edge]), MT tiles/wave.
template<int MT, int K, int N, bool ACT, bool ENVMUL, int LDI, int LDO>
__device__ __forceinline__ void wave_layer(const unsigned short* __restrict__ WT,
                                           const unsigned short* actIn,
                                           unsigned short* actOut,
                                           const float* sEnv) {
  const int lane = threadIdx.x & 63;
  const int w = threadIdx.x >> 6;
  const int l15 = lane & 15;
  const int q = lane >> 4;
  const int kb = q * 8;
  constexpr int KT = K / 32;
  constexpr int NT = N / 16;
  s16x8 b[MT][KT];
#pragma unroll
  for (int m = 0; m < MT; ++m)
#pragma unroll
    for (int kt = 0; kt < KT; ++kt)
      b[m][kt] = ld_frag(actIn + (w * 16 * MT + m * 16 + l15) * LDI + kt * 32 + kb);
  float envr[MT];
  if (ENVMUL) {
#pragma unroll
    for (int m = 0; m < MT; ++m) envr[m] = sEnv[w * 16 * MT + m * 16 + l15];
  }
#pragma unroll
  for (int nt = 0; nt < NT; ++nt) {
    const unsigned short* wp = WT + (nt * 16 + l15) * K + kb;
    f32x4 acc[MT];
#pragma unroll
    for (int m = 0; m < MT; ++m) acc[m] = (f32x4){0.f, 0.f, 0.f, 0.f};
    __builtin_amdgcn_s_setprio(1);
#pragma unroll
    for (int kt = 0; kt < KT; ++kt) {
      s16x8 wf = ld_frag(wp + kt * 32);
#pragma unroll
      for (int m = 0; m < MT; ++m)
        acc[m] = __builtin_amdgcn_mfma_f32_16x16x32_bf16(wf, b[m][kt], acc[m], 0, 0, 0);
    }
    __builtin_amdgcn_s_setprio(0);
#pragma unroll
    for (int m = 0; m < MT; ++m) {
      const int row = w * 16 * MT + m * 16 + l15;
      float v[4];
#pragma unroll
      for (int r = 0; r < 4; ++r) {
        float x = acc[m][r];
        if (ENVMUL) x *= envr[m];
        v[r] = ACT ? silu_f(x) : x;
      }
      *(uint2*)(actOut + row * LDO + nt * 16 + q * 4) = pack4(v[0], v[1], v[2], v[3]);
    }
  }
}

// ---- w = x @ Ww (K=64, scale folded): bf16 packed stores into wg. ----
template<bool WITH_WV, int MT, int LDI>
__device__ __forceinline__ void w_store(const unsigned short* __restrict__ WT,
                                        const unsigned short* actIn,
                                        unsigned short* __restrict__ wg,
                                        float* __restrict__ wvg, int e0) {
  const int lane = threadIdx.x & 63;
  const int w = threadIdx.x >> 6;
  const int l15 = lane & 15;
  const int q = lane >> 4;
  const int kb = q * 8;
  s16x8 b0[MT], b1[MT];
#pragma unroll
  for (int m = 0; m < MT; ++m) {
    const int row = w * 16 * MT + m * 16 + l15;
    b0[m] = ld_frag(actIn + row * LDI + kb);
    b1[m] = ld_frag(actIn + row * LDI + 32 + kb);
  }
  constexpr int NT = WITH_WV ? 3 : 2;
#pragma unroll
  for (int nt = 0; nt < NT; ++nt) {
    const unsigned short* wp = WT + (nt * 16 + l15) * 64 + kb;
    s16x8 wf0 = ld_frag(wp);
    s16x8 wf1 = ld_frag(wp + 32);
    __builtin_amdgcn_s_setprio(1);
#pragma unroll
    for (int m = 0; m < MT; ++m) {
      f32x4 acc = {0.f, 0.f, 0.f, 0.f};
      acc = __builtin_amdgcn_mfma_f32_16x16x32_bf16(wf0, b0[m], acc, 0, 0, 0);
      acc = __builtin_amdgcn_mfma_f32_16x16x32_bf16(wf1, b1[m], acc, 0, 0, 0);
      const int row = w * 16 * MT + m * 16 + l15;
      if (nt < 2) {
        *(uint2*)(wg + (size_t)(e0 + row) * 32 + nt * 16 + q * 4) =
            pack4(acc[0], acc[1], acc[2], acc[3]);
      } else if (q == 0) {
        wvg[e0 + row] = acc[0];
      }
    }
    __builtin_amdgcn_s_setprio(0);
  }
}

// WT layout offsets (ushort units)
#define OFF_E0   0      // [64][96]
#define OFF_E1   6144   // [128][64]
#define OFF_E2   14336  // [256][128]
#define OFF_E3   47104  // [64][256]
#define OFF_W0   63488  // [48][64]  (col 32 = Wwvec)
#define OFF_W1   66560  // [32][64]
#define OFF_M00  68608  // [64][96]
#define OFF_M01  74752
#define OFF_M10  80896  // [64][64]
#define OFF_M11  84992
#define OFF_M20  89088
#define OFF_M21  93184  // (unused after vr2 collapse)
#define OFF_V0   97280  // [32][32]
#define WT_END   99328

// ---- prep (blocks 0..14) + out-init/cursor-zero (blocks 15..54), merged ----
__global__ void kprep_init(const float* __restrict__ We0, const float* __restrict__ We1,
                           const float* __restrict__ We2, const float* __restrict__ We3,
                           const float* __restrict__ Wwvec, const float* __restrict__ Ww,
                           const float* __restrict__ Wm0, const float* __restrict__ Wm1,
                           const float* __restrict__ Wm2, const float* __restrict__ WV,
                           const float* __restrict__ Wr0, const float* __restrict__ Wrout,
                           unsigned short* __restrict__ WT, float* __restrict__ vr,
                           int* __restrict__ cursor,
                           float* __restrict__ out, const int* __restrict__ species,
                           const float* __restrict__ pe) {
  const int b = blockIdx.x, t = threadIdx.x;
  if (b >= 15) {
    int i = (b - 15) * 256 + t;
    if (i < N_NODES) { out[i] = pe[species[i]]; cursor[i] = 0; cursor[N_NODES + i] = 0; }
    return;
  }
  if (b == 4) {
    unsigned short* d4 = WT + OFF_W0;
    for (int idx = t; idx < 48 * 64; idx += 256) {
      int n = idx >> 6, k = idx & 63;
      float v = (n < 32) ? Ww[k * 32 + n] * 0.125f
                         : ((n == 32) ? Wwvec[k] * 0.125f : 0.f);
      d4[n * 64 + k] = f2b(v);
    }
    return;
  }
  if (b == 14) {
    __shared__ float tmp[64];
    if (t < 64) {
      float s = 0.f;
      for (int j = 0; j < 64; ++j) s += Wr0[t * 64 + j] * Wrout[j];
      tmp[t] = s;
    }
    __syncthreads();
    if (t < 64) {
      const float* Wm2b = Wm2 + 4096;  // l=1 block
      float s2 = 0.f;
      for (int n = 0; n < 64; ++n) s2 += Wm2b[t * 64 + n] * tmp[n];
      vr[t] = s2;
    }
    return;
  }
  const float* src = nullptr; unsigned short* dst = nullptr;
  int KIN = 0, N = 0, KP = 0; float scl = 1.f;
  switch (b) {
    case 0:  src = We0;        dst = WT + OFF_E0;  KIN = 72;  N = 64;  KP = 96;  scl = 0.11785113f; break;
    case 1:  src = We1;        dst = WT + OFF_E1;  KIN = 64;  N = 128; KP = 64;  scl = 0.125f; break;
    case 2:  src = We2;        dst = WT + OFF_E2;  KIN = 128; N = 256; KP = 128; scl = 0.08838835f; break;
    case 3:  src = We3;        dst = WT + OFF_E3;  KIN = 256; N = 64;  KP = 256; scl = 0.0625f; break;
    case 5:  src = Ww + 2048;  dst = WT + OFF_W1;  KIN = 64;  N = 32;  KP = 64;  scl = 0.125f; break;
    case 6:  src = Wm0;        dst = WT + OFF_M00; KIN = 96;  N = 64;  KP = 96;  scl = 0.10206207f; break;
    case 7:  src = Wm0 + 6144; dst = WT + OFF_M01; KIN = 96;  N = 64;  KP = 96;  scl = 0.10206207f; break;
    case 8:  src = Wm1;        dst = WT + OFF_M10; KIN = 64;  N = 64;  KP = 64;  scl = 0.125f; break;
    case 9:  src = Wm1 + 4096; dst = WT + OFF_M11; KIN = 64;  N = 64;  KP = 64;  scl = 0.125f; break;
    case 10: src = Wm2;        dst = WT + OFF_M20; KIN = 64;  N = 64;  KP = 64;  scl = 0.125f; break;
    case 12: src = WV;         dst = WT + OFF_V0;  KIN = 32;  N = 32;  KP = 32;  scl = 0.17677669529663689f; break;
    default: return;
  }
  for (int idx = t; idx < N * KP; idx += 256) {
    int n = idx / KP, k = idx - n * KP;
    float v = (k < KIN) ? src[k * N + n] * scl : 0.f;
    dst[n * KP + k] = f2b(v);
  }
}

// -------------------- gather: 32 lanes/node; 2-edge pipelined bucket walk ------
__global__ __launch_bounds__(256) void kgather(const int* __restrict__ cursor,
                                               const int* __restrict__ bucket,
                                               const unsigned short* __restrict__ wg,
                                               const float* __restrict__ yg,
                                               unsigned short* __restrict__ nwY) {
  const int n = blockIdx.x * 8 + (threadIdx.x >> 5);
  const int c = threadIdx.x & 31;
  const int cnt = cursor[n];
  const int* bk = bucket + (size_t)n * CAP;
  float a0 = 0.f, a1 = 0.f, a2 = 0.f, a3 = 0.f;
  int ea = (cnt > 0) ? __builtin_amdgcn_readfirstlane(bk[0]) : 0;
  int eb = (cnt > 1) ? __builtin_amdgcn_readfirstlane(bk[1]) : 0;
  int i = 0;
  for (; i + 2 <= cnt; i += 2) {
    int ec = (i + 2 < cnt) ? __builtin_amdgcn_readfirstlane(bk[i + 2]) : 0;
    int ed = (i + 3 < cnt) ? __builtin_amdgcn_readfirstlane(bk[i + 3]) : 0;
    float wa = b2f(wg[(size_t)ea * 32 + c]);
    float4 ya = ((const float4*)yg)[ea];
    float wb = b2f(wg[(size_t)eb * 32 + c]);
    float4 yb = ((const float4*)yg)[eb];
    a0 += wa + wb;
    a1 = fmaf(wa, ya.x, fmaf(wb, yb.x, a1));
    a2 = fmaf(wa, ya.y, fmaf(wb, yb.y, a2));
    a3 = fmaf(wa, ya.z, fmaf(wb, yb.z, a3));
    ea = ec; eb = ed;
  }
  if (i < cnt) {
    float wa = b2f(wg[(size_t)ea * 32 + c]);
    float4 ya = ((const float4*)yg)[ea];
    a0 += wa;
    a1 = fmaf(wa, ya.x, a1);
    a2 = fmaf(wa, ya.y, a2);
    a3 = fmaf(wa, ya.z, a3);
  }
  *(uint2*)(nwY + (size_t)n * 128 + c * 4) = pack4(a0, a1, a2, a3);
}

#define LDA1 104   // 96 staging cols + pad; x2 never materialized (two-half E1)
#define LDA2 104
#define EPB 256    // edges per block (4 waves x 64, MT=4) -- exploits wg-slot cap
#define SCR 64     // E2 chunk scratch base col in k1

// -------------------- K1: edge MLP (MT=4, 4 waves; fills bucket inline) ----------
__global__ __launch_bounds__(256, 1) void k1_edge(
    const float* __restrict__ vectors, const int* __restrict__ senders,
    const int* __restrict__ receivers, const int* __restrict__ species,
    const float* __restrict__ emb, const unsigned short* __restrict__ WT,
    unsigned short* __restrict__ xg, float* __restrict__ wvg,
    unsigned short* __restrict__ wg, float* __restrict__ yg,
    int* __restrict__ cursor, int* __restrict__ bucket) {
  __shared__ __align__(16) unsigned short bufA[EPB * LDA1];
  __shared__ float sEnv[EPB];
  const int t = threadIdx.x;
  const int lane = t & 63;
  const int w = t >> 6;
  const int l15 = lane & 15;
  const int q = lane >> 4;
  const int kb = q * 8;
  const int e0 = blockIdx.x * EPB;
  const int row = t;                 // 1 lane per edge
  const int eg = e0 + row;

  // staging: 1 lane per edge (cols 0..95) + inline bucket fill
  {
    float vx = vectors[3 * eg], vy = vectors[3 * eg + 1], vz = vectors[3 * eg + 2];
    float dd = fmaxf(sqrtf(vx * vx + vy * vy + vz * vz), 1e-6f);
    float d2 = dd * dd, d6 = d2 * d2 * d2;
    float env = (dd < 1.f) ? (1.f + d6 * (-28.f + 48.f * dd - 21.f * d2)) : 0.f;
    float inv_d = 1.f / dd;
    {
      const float SQ3 = 1.7320508075688772f;
      float4 yv;
      yv.x = SQ3 * vx * inv_d; yv.y = SQ3 * vy * inv_d; yv.z = SQ3 * vz * inv_d;
      yv.w = env;
      ((float4*)yg)[eg] = yv;
      sEnv[row] = env;
    }
    float c = 1.4142135623730951f * env * inv_d;
    const float PI_F = 3.14159265358979323846f;
#pragma unroll
    for (int n = 0; n < 4; ++n) {
      float s0 = c * __sinf((float)(n + 1) * PI_F * dd);
      float s1 = c * __sinf((float)(n + 5) * PI_F * dd);
      bufA[row * LDA1 + n] = f2b(s0);
      bufA[row * LDA1 + n + 4] = f2b(s1);
    }
    int snd = senders[eg];
    int pos = atomicAdd(&cursor[snd], 1);
    bucket[(size_t)snd * CAP + pos] = eg;
    int ss = species[snd];
    int sr = species[receivers[eg]];
    const float4* es = (const float4*)(emb + ss * 32);
    const float4* er = (const float4*)(emb + sr * 32);
#pragma unroll
    for (int it = 0; it < 8; ++it) {
      float4 zs = es[it];
      float4 zr = er[it];
      uint2 ps, pr;
      ps.x = (unsigned)f2b(zs.x) | ((unsigned)f2b(zs.y) << 16);
      ps.y = (unsigned)f2b(zs.z) | ((unsigned)f2b(zs.w) << 16);
      pr.x = (unsigned)f2b(zr.x) | ((unsigned)f2b(zr.y) << 16);
      pr.y = (unsigned)f2b(zr.z) | ((unsigned)f2b(zr.w) << 16);
      *(uint2*)(bufA + row * LDA1 + 8 + it * 4) = ps;
      *(uint2*)(bufA + row * LDA1 + 40 + it * 4) = pr;
    }
    uint4 zz = {0, 0, 0, 0};
    *(uint4*)(bufA + row * LDA1 + 72) = zz;
    *(uint4*)(bufA + row * LDA1 + 80) = zz;
    *(uint4*)(bufA + row * LDA1 + 88) = zz;
  }

  wave_layer<4, 96, 64, true, false, LDA1, LDA1>(WT + OFF_E0, bufA, bufA, nullptr);

  // E1 (64->128, silu) in two half-passes: input pre-read into b1 regs.
  s16x8 b1[4][2];
#pragma unroll
  for (int m = 0; m < 4; ++m)
#pragma unroll
    for (int kt = 0; kt < 2; ++kt)
      b1[m][kt] = ld_frag(bufA + (w * 64 + m * 16 + l15) * LDA1 + kt * 32 + kb);
  s16x8 a2[4][4];
#pragma unroll
  for (int half = 0; half < 2; ++half) {
    const unsigned short* WTh = WT + OFF_E1 + half * (64 * 64);
#pragma unroll
    for (int nt = 0; nt < 4; ++nt) {
      const unsigned short* wp = WTh + (nt * 16 + l15) * 64 + kb;
      s16x8 wf0 = ld_frag(wp);
      s16x8 wf1 = ld_frag(wp + 32);
      __builtin_amdgcn_s_setprio(1);
#pragma unroll
      for (int m = 0; m < 4; ++m) {
        f32x4 acc = {0.f, 0.f, 0.f, 0.f};
        acc = __builtin_amdgcn_mfma_f32_16x16x32_bf16(wf0, b1[m][0], acc, 0, 0, 0);
        acc = __builtin_amdgcn_mfma_f32_16x16x32_bf16(wf1, b1[m][1], acc, 0, 0, 0);
        const int rr = w * 64 + m * 16 + l15;
        *(uint2*)(bufA + rr * LDA1 + nt * 16 + q * 4) =
            pack4(silu_f(acc[0]), silu_f(acc[1]), silu_f(acc[2]), silu_f(acc[3]));
      }
      __builtin_amdgcn_s_setprio(0);
    }
#pragma unroll
    for (int m = 0; m < 4; ++m)
#pragma unroll
      for (int kt = 0; kt < 2; ++kt)
        a2[m][half * 2 + kt] =
            ld_frag(bufA + (w * 64 + m * 16 + l15) * LDA1 + kt * 32 + kb);
  }

  // fused E2 (128->256, silu) + E3 (256->64), MT=4; scratch cols 64..95.
  f32x4 acc3[4][4];
#pragma unroll
  for (int m = 0; m < 4; ++m)
#pragma unroll
    for (int nt = 0; nt < 4; ++nt) acc3[m][nt] = (f32x4){0.f, 0.f, 0.f, 0.f};
#pragma unroll 2
  for (int cc = 0; cc < 8; ++cc) {
    s16x8 e3wf[4];
#pragma unroll
    for (int nt = 0; nt < 4; ++nt)
      e3wf[nt] = ld_frag(WT + OFF_E3 + (nt * 16 + l15) * 256 + cc * 32 + kb);
#pragma unroll
    for (int nt = 0; nt < 2; ++nt) {
      const unsigned short* wp = WT + OFF_E2 + ((cc * 2 + nt) * 16 + l15) * 128 + kb;
      f32x4 acc[4];
#pragma unroll
      for (int m = 0; m < 4; ++m) acc[m] = (f32x4){0.f, 0.f, 0.f, 0.f};
      __builtin_amdgcn_s_setprio(1);
#pragma unroll
      for (int kt = 0; kt < 4; ++kt) {
        s16x8 wf = ld_frag(wp + kt * 32);
#pragma unroll
        for (int m = 0; m < 4; ++m)
          acc[m] = __builtin_amdgcn_mfma_f32_16x16x32_bf16(wf, a2[m][kt], acc[m], 0, 0, 0);
      }
      __builtin_amdgcn_s_setprio(0);
#pragma unroll
      for (int m = 0; m < 4; ++m) {
        const int rr = w * 64 + m * 16 + l15;
        *(uint2*)(bufA + rr * LDA1 + SCR + nt * 16 + q * 4) =
            pack4(silu_f(acc[m][0]), silu_f(acc[m][1]), silu_f(acc[m][2]), silu_f(acc[m][3]));
      }
    }
    __builtin_amdgcn_s_setprio(1);
#pragma unroll
    for (int m = 0; m < 4; ++m) {
      s16x8 aa = ld_frag(bufA + (w * 64 + m * 16 + l15) * LDA1 + SCR + kb);
#pragma unroll
      for (int nt = 0; nt < 4; ++nt)
        acc3[m][nt] = __builtin_amdgcn_mfma_f32_16x16x32_bf16(e3wf[nt], aa, acc3[m][nt], 0, 0, 0);
    }
    __builtin_amdgcn_s_setprio(0);
  }
  // epilogue: x = env * x3 -> bufA cols 0..63
#pragma unroll
  for (int m = 0; m < 4; ++m) {
    const int rr = w * 64 + m * 16 + l15;
    const float env = sEnv[rr];
#pragma unroll
    for (int nt = 0; nt < 4; ++nt)
      *(uint2*)(bufA + rr * LDA1 + nt * 16 + q * 4) =
          pack4(acc3[m][nt][0] * env, acc3[m][nt][1] * env,
                acc3[m][nt][2] * env, acc3[m][nt][3] * env);
  }
  // vectorized copy own rows -> xg (wave w: rows w*64..w*64+63)
#pragma unroll
  for (int it = 0; it < 8; ++it) {
    int idx = it * 64 + lane;
    int e_l = w * 64 + (idx >> 3), ch = idx & 7;
    *(uint4*)(xg + (size_t)(e0 + e_l) * 64 + ch * 8) =
        *(const uint4*)(bufA + e_l * LDA1 + ch * 8);
  }
  w_store<true, 4, LDA1>(WT + OFF_W0, bufA, wg, wvg, e0);
}

// -------------------- K2: layer l=0 (MT=4, 4 waves; bf16 nwY) ----------
__global__ __launch_bounds__(256, 1) void k2_layer0(
    const int* __restrict__ senders, const float* __restrict__ Wvinit,
    const unsigned short* __restrict__ WT, unsigned short* __restrict__ xg,
    const float* __restrict__ wvg, unsigned short* __restrict__ h1g,
    const unsigned short* __restrict__ nwY0, unsigned short* __restrict__ wg,
    const float* __restrict__ yg, const float* __restrict__ vepsp) {
  __shared__ __align__(16) unsigned short bufA[EPB * LDA2];
  __shared__ float sEnv[EPB];
  const int t = threadIdx.x;
  const int lane = t & 63;
  const int w = t >> 6;
  const int l15 = lane & 15;
  const int q = lane >> 4;
  const int kb = q * 8;
  const int e0 = blockIdx.x * EPB;
  const float eps = rsqrtf(1.f + log1pf(__expf(vepsp[0])));

  // (a) stage sout (cols 64..95) + hcb (cols 0..31); 1 lane per edge
  {
    const int row = t;
    const int ee = e0 + row;
    int snd = senders[ee];
    float4 y = ((const float4*)yg)[ee];
    float wvc = wvg[ee] * (1.f / 66.f);
    sEnv[row] = y.w;
    const unsigned short* nwp = nwY0 + (size_t)snd * 128;
    const float IS3 = 0.57735026918962576f;
#pragma unroll 4
    for (int j = 0; j < 16; ++j) {
      int c = 2 * j;
      U16x8 nw; nw.u = *(const uint4*)(nwp + c * 4);
      float h0a = wvc * Wvinit[c];
      float h0b = wvc * Wvinit[c + 1];
      float ska = b2f((unsigned short)nw.s[1]) * y.x + b2f((unsigned short)nw.s[2]) * y.y
                + b2f((unsigned short)nw.s[3]) * y.z;
      float skb = b2f((unsigned short)nw.s[5]) * y.x + b2f((unsigned short)nw.s[6]) * y.y
                + b2f((unsigned short)nw.s[7]) * y.z;
      unsigned pa = (unsigned)f2b(h0a * eps * ska * IS3) |
                    ((unsigned)f2b(h0b * eps * skb * IS3) << 16);
      *(unsigned*)(bufA + row * LDA2 + 64 + c) = pa;
      unsigned pb = (unsigned)f2b(eps * b2f((unsigned short)nw.s[0]) * h0a) |
                    ((unsigned)f2b(eps * b2f((unsigned short)nw.s[4]) * h0b) << 16);
      *(unsigned*)(bufA + row * LDA2 + c) = pb;
    }
  }
  // (b) V-layer (32x32, swapped) reads hcb from cols 0..31 -> h1g
  __builtin_amdgcn_s_setprio(1);
#pragma unroll
  for (int m = 0; m < 4; ++m) {
    const int rr = w * 64 + m * 16 + l15;
    s16x8 b0 = ld_frag(bufA + rr * LDA2 + kb);
#pragma unroll
    for (int nt = 0; nt < 2; ++nt) {
      f32x4 acc = {0.f, 0.f, 0.f, 0.f};
      acc = __builtin_amdgcn_mfma_f32_16x16x32_bf16(
          ld_frag(WT + OFF_V0 + (nt * 16 + l15) * 32 + kb), b0, acc, 0, 0, 0);
      *(uint2*)(h1g + (size_t)(e0 + rr) * 32 + nt * 16 + q * 4) =
          pack4(acc[0], acc[1], acc[2], acc[3]);
    }
  }
  __builtin_amdgcn_s_setprio(0);
  // (c) load x into cols 0..63 (overwrites hcb; same-wave ordering keeps it safe)
#pragma unroll
  for (int it = 0; it < 8; ++it) {
    int idx = it * 64 + lane;
    int e_l = w * 64 + (idx >> 3), ch = idx & 7;
    *(uint4*)(bufA + e_l * LDA2 + ch * 8) =
        *(const uint4*)(xg + (size_t)(e0 + e_l) * 64 + ch * 8);
  }
  wave_layer<4, 96, 64, true, false, LDA2, LDA2>(WT + OFF_M00, bufA, bufA, nullptr);
  wave_layer<4, 64, 64, true, false, LDA2, LDA2>(WT + OFF_M10, bufA, bufA, nullptr);
  wave_layer<4, 64, 64, false, true, LDA2, LDA2>(WT + OFF_M20, bufA, bufA, sEnv);
#pragma unroll
  for (int it = 0; it < 8; ++it) {
    int idx = it * 64 + lane;
    int e_l = w * 64 + (idx >> 3), ch = idx & 7;
    *(uint4*)(xg + (size_t)(e0 + e_l) * 64 + ch * 8) =
        *(const uint4*)(bufA + e_l * LDA2 + ch * 8);
  }
  w_store<false, 4, LDA2>(WT + OFF_W1, bufA, wg, nullptr, e0);
}

// -------------------- K3: layer l=1 + readout (MT=4, 4 waves) ------------
__global__ __launch_bounds__(256, 1) void k3_layer1(
    const int* __restrict__ senders, const int* __restrict__ receivers,
    const unsigned short* __restrict__ WT, const float* __restrict__ vr,
    const unsigned short* __restrict__ xg, const unsigned short* __restrict__ h1g,
    const unsigned short* __restrict__ nwY1, const float* __restrict__ yg,
    float* __restrict__ out, const float* __restrict__ vepsp) {
  __shared__ __align__(16) unsigned short bufA[EPB * LDA2];
  __shared__ float sEnv[EPB];
  const int t = threadIdx.x;
  const int lane = t & 63;
  const int w = t >> 6;
  const int e0 = blockIdx.x * EPB;
  const float eps = rsqrtf(1.f + log1pf(__expf(vepsp[0])));

  // (a) random-latency staging FIRST (nwY1 + h1g) -> cols 64..95
  {
    const int row = t;
    const int ee = e0 + row;
    int snd = senders[ee];
    float4 y = ((const float4*)yg)[ee];
    sEnv[row] = y.w;
    const unsigned short* nwp = nwY1 + (size_t)snd * 128;
    U16x8 hv[4];
#pragma unroll
    for (int h = 0; h < 4; ++h)
      hv[h].u = *(const uint4*)(h1g + (size_t)ee * 32 + h * 8);
    const float IS3 = 0.57735026918962576f;
#pragma unroll 4
    for (int j = 0; j < 16; ++j) {
      int c = 2 * j;
      U16x8 nw; nw.u = *(const uint4*)(nwp + c * 4);
      float hca = b2f((unsigned short)hv[c >> 3].s[c & 7]);
      float hcb2 = b2f((unsigned short)hv[(c + 1) >> 3].s[(c + 1) & 7]);
      float ska = b2f((unsigned short)nw.s[1]) * y.x + b2f((unsigned short)nw.s[2]) * y.y
                + b2f((unsigned short)nw.s[3]) * y.z;
      float skb = b2f((unsigned short)nw.s[5]) * y.x + b2f((unsigned short)nw.s[6]) * y.y
                + b2f((unsigned short)nw.s[7]) * y.z;
      unsigned pa = (unsigned)f2b(hca * eps * ska * IS3) |
                    ((unsigned)f2b(hcb2 * eps * skb * IS3) << 16);
      *(unsigned*)(bufA + row * LDA2 + 64 + c) = pa;
    }
  }
  // (b) sequential x-load -> cols 0..63 (disjoint cols, same wave rows)
#pragma unroll
  for (int it = 0; it < 8; ++it) {
    int idx = it * 64 + lane;
    int e_l = w * 64 + (idx >> 3), ch = idx & 7;
    *(uint4*)(bufA + e_l * LDA2 + ch * 8) =
        *(const uint4*)(xg + (size_t)(e0 + e_l) * 64 + ch * 8);
  }
  wave_layer<4, 96, 64, true, false, LDA2, LDA2>(WT + OFF_M01, bufA, bufA, nullptr);
  wave_layer<4, 64, 64, true, false, LDA2, LDA2>(WT + OFF_M11, bufA, bufA, nullptr);
  // readout on M11 output (M21 + Wr0 + Wrout collapsed into vr2)
  {
    const int row = t;
    float dot = 0.f;
#pragma unroll
    for (int h = 0; h < 8; ++h) {
      U16x8 xv; xv.u = *(const uint4*)(bufA + row * LDA2 + h * 8);
#pragma unroll
      for (int j = 0; j < 8; ++j)
        dot = fmaf(b2f((unsigned short)xv.s[j]), vr[h * 8 + j], dot);
    }
    float env = sEnv[row];
    int rcv = receivers[e0 + row];
    atomAddF(out + rcv, dot * 0.001953125f * env * env);
  }
}

// -------------------- launch --------------------
extern "C" void kernel_launch(void* const* d_in, const int* in_sizes, int n_in,
                              void* d_out, int out_size, void* d_ws, size_t ws_size,
                              hipStream_t stream) {
  const float* vectors   = (const float*)d_in[0];
  const int*   senders   = (const int*)d_in[1];
  const int*   receivers = (const int*)d_in[2];
  const int*   species   = (const int*)d_in[3];
  const float* emb       = (const float*)d_in[4];
  const float* We0       = (const float*)d_in[5];
  const float* We1       = (const float*)d_in[6];
  const float* We2       = (const float*)d_in[7];
  const float* We3       = (const float*)d_in[8];
  const float* Wwvec     = (const float*)d_in[9];
  const float* Wvinit    = (const float*)d_in[10];
  const float* Ww        = (const float*)d_in[11];
  const float* Wm0       = (const float*)d_in[12];
  const float* Wm1       = (const float*)d_in[13];
  const float* Wm2       = (const float*)d_in[14];
  const float* WV        = (const float*)d_in[15];
  const float* Wr0       = (const float*)d_in[16];
  const float* Wrout     = (const float*)d_in[17];
  const float* pe        = (const float*)d_in[18];
  const float* veps      = (const float*)d_in[19];
  float* outp = (float*)d_out;

  unsigned short* wsu = (unsigned short*)d_ws;
  unsigned short* WT  = wsu;
  float* vr           = (float*)(wsu + WT_END);
  unsigned short* xg  = wsu + WT_END + 128;                   // E*64 bf16
  unsigned short* h1g = xg + (size_t)E_EDGES * 64;            // E*32 bf16
  unsigned short* wg  = h1g + (size_t)E_EDGES * 32;           // E*32 bf16
  float* wvg          = (float*)(wg + (size_t)E_EDGES * 32);  // E f32
  float* yg           = wvg + E_EDGES;                        // E*4 f32 (Y1,env)
  unsigned short* nwY0 = (unsigned short*)(yg + (size_t)E_EDGES * 4); // N*128 bf16
  unsigned short* nwY1 = nwY0 + N_NODES * 128;                // N*128 bf16
  int* cursor         = (int*)(nwY1 + N_NODES * 128);         // 2*N
  int* bucket         = cursor + 2 * N_NODES;                 // N*CAP

  const int nblk = E_EDGES / EPB;  // 1250

  hipLaunchKernelGGL(kprep_init, dim3(15 + (N_NODES + 255) / 256), dim3(256), 0, stream,
                     We0, We1, We2, We3, Wwvec, Ww, Wm0, Wm1, Wm2, WV, Wr0, Wrout,
                     WT, vr, cursor, outp, species, pe);
  hipLaunchKernelGGL(k1_edge, dim3(nblk), dim3(256), 0, stream,
                     vectors, senders, receivers, species, emb, WT, xg, wvg, wg, yg,
                     cursor, bucket);
  hipLaunchKernelGGL(kgather, dim3(N_NODES / 8), dim3(256), 0, stream,
                     cursor, bucket, wg, yg, nwY0);
  hipLaunchKernelGGL(k2_layer0, dim3(nblk), dim3(256), 0, stream,
                     senders, Wvinit, WT, xg, wvg, h1g, nwY0, wg, yg, veps);
  hipLaunchKernelGGL(kgather, dim3(N_NODES / 8), dim3(256), 0, stream,
                     cursor, bucket, wg, yg, nwY1);
  hipLaunchKernelGGL(k3_layer1, dim3(nblk), dim3(256), 0, stream,
                     senders, receivers, WT, vr, xg, h1g, nwY1, yg, outp, veps);
}

// Round 22
// 290.163 us; speedup vs baseline: 1.0204x; 1.0204x over previous
//
#include <hip/hip_runtime.h>
#include <math.h>

#define E_EDGES 320000
#define N_NODES 10000
#define CAP 128   // bucket capacity per node (Poisson(32), max deg ~60)

typedef __attribute__((ext_vector_type(4))) float f32x4;
typedef __attribute__((ext_vector_type(8))) short s16x8;

__device__ __forceinline__ float silu_f(float v) {
  return v * __builtin_amdgcn_rcpf(1.f + __expf(-v));
}

__device__ __forceinline__ void atomAddF(float* p, float v) {
  __hip_atomic_fetch_add(p, v, __ATOMIC_RELAXED, __HIP_MEMORY_SCOPE_AGENT);
}

__device__ __forceinline__ unsigned short f2b(float x) {
  __bf16 h = (__bf16)x;
  return __builtin_bit_cast(unsigned short, h);
}
__device__ __forceinline__ float b2f(unsigned short h) {
  return __uint_as_float(((unsigned)h) << 16);
}
__device__ __forceinline__ uint2 pack4(float a, float b, float c, float d) {
  uint2 p;
  p.x = (unsigned)f2b(a) | ((unsigned)f2b(b) << 16);
  p.y = (unsigned)f2b(c) | ((unsigned)f2b(d) << 16);
  return p;
}

union U16x8 { uint4 u; s16x8 s; };
__device__ __forceinline__ s16x8 ld_frag(const unsigned short* p) {
  U16x8 x; x.u = *(const uint4*)p; return x.s;
}

// ---- MFMA dense layer, swapped operands (D[feature][edge]), MT tiles/wave.
template<int MT, int K, int N, bool ACT, bool ENVMUL, int LDI, int LDO>
__device__ __forceinline__ void wave_layer(const unsigned short* __restrict__ WT,
                                           const unsigned short* actIn,
                                           unsigned short* actOut,
                                           const float* sEnv) {
  const int lane = threadIdx.x & 63;
  const int w = threadIdx.x >> 6;
  const int l15 = lane & 15;
  const int q = lane >> 4;
  const int kb = q * 8;
  constexpr int KT = K / 32;
  constexpr int NT = N / 16;
  s16x8 b[MT][KT];
#pragma unroll
  for (int m = 0; m < MT; ++m)
#pragma unroll
    for (int kt = 0; kt < KT; ++kt)
      b[m][kt] = ld_frag(actIn + (w * 16 * MT + m * 16 + l15) * LDI + kt * 32 + kb);
  float envr[MT];
  if (ENVMUL) {
#pragma unroll
    for (int m = 0; m < MT; ++m) envr[m] = sEnv[w * 16 * MT + m * 16 + l15];
  }
#pragma unroll
  for (int nt = 0; nt < NT; ++nt) {
    const unsigned short* wp = WT + (nt * 16 + l15) * K + kb;
    f32x4 acc[MT];
#pragma unroll
    for (int m = 0; m < MT; ++m) acc[m] = (f32x4){0.f, 0.f, 0.f, 0.f};
    __builtin_amdgcn_s_setprio(1);
#pragma unroll
    for (int kt = 0; kt < KT; ++kt) {
      s16x8 wf = ld_frag(wp + kt * 32);
#pragma unroll
      for (int m = 0; m < MT; ++m)
        acc[m] = __builtin_amdgcn_mfma_f32_16x16x32_bf16(wf, b[m][kt], acc[m], 0, 0, 0);
    }
    __builtin_amdgcn_s_setprio(0);
#pragma unroll
    for (int m = 0; m < MT; ++m) {
      const int row = w * 16 * MT + m * 16 + l15;
      float v[4];
#pragma unroll
      for (int r = 0; r < 4; ++r) {
        float x = acc[m][r];
        if (ENVMUL) x *= envr[m];
        v[r] = ACT ? silu_f(x) : x;
      }
      *(uint2*)(actOut + row * LDO + nt * 16 + q * 4) = pack4(v[0], v[1], v[2], v[3]);
    }
  }
}

// ---- w = x @ Ww (K=64, scale folded): bf16 packed stores into wg. ----
template<bool WITH_WV, int MT, int LDI>
__device__ __forceinline__ void w_store(const unsigned short* __restrict__ WT,
                                        const unsigned short* actIn,
                                        unsigned short* __restrict__ wg,
                                        float* __restrict__ wvg, int e0) {
  const int lane = threadIdx.x & 63;
  const int w = threadIdx.x >> 6;
  const int l15 = lane & 15;
  const int q = lane >> 4;
  const int kb = q * 8;
  s16x8 b0[MT], b1[MT];
#pragma unroll
  for (int m = 0; m < MT; ++m) {
    const int row = w * 16 * MT + m * 16 + l15;
    b0[m] = ld_frag(actIn + row * LDI + kb);
    b1[m] = ld_frag(actIn + row * LDI + 32 + kb);
  }
  constexpr int NT = WITH_WV ? 3 : 2;
#pragma unroll
  for (int nt = 0; nt < NT; ++nt) {
    const unsigned short* wp = WT + (nt * 16 + l15) * 64 + kb;
    s16x8 wf0 = ld_frag(wp);
    s16x8 wf1 = ld_frag(wp + 32);
    __builtin_amdgcn_s_setprio(1);
#pragma unroll
    for (int m = 0; m < MT; ++m) {
      f32x4 acc = {0.f, 0.f, 0.f, 0.f};
      acc = __builtin_amdgcn_mfma_f32_16x16x32_bf16(wf0, b0[m], acc, 0, 0, 0);
      acc = __builtin_amdgcn_mfma_f32_16x16x32_bf16(wf1, b1[m], acc, 0, 0, 0);
      const int row = w * 16 * MT + m * 16 + l15;
      if (nt < 2) {
        *(uint2*)(wg + (size_t)(e0 + row) * 32 + nt * 16 + q * 4) =
            pack4(acc[0], acc[1], acc[2], acc[3]);
      } else if (q == 0) {
        wvg[e0 + row] = acc[0];
      }
    }
    __builtin_amdgcn_s_setprio(0);
  }
}

// WT layout offsets (ushort units)
#define OFF_E0   0      // [64][96]
#define OFF_E1   6144   // [128][64]
#define OFF_E2   14336  // [256][128]
#define OFF_E3   47104  // [64][256]
#define OFF_W0   63488  // [48][64]  (col 32 = Wwvec)
#define OFF_W1   66560  // [32][64]
#define OFF_M00  68608  // [64][96]
#define OFF_M01  74752
#define OFF_M10  80896  // [64][64]
#define OFF_M11  84992
#define OFF_M20  89088
#define OFF_M21  93184  // (unused after vr2 collapse)
#define OFF_V0   97280  // [32][32]
#define WT_END   99328

// ---- prep (blocks 0..14) + out-init/cursor-zero (blocks 15..54), merged ----
__global__ void kprep_init(const float* __restrict__ We0, const float* __restrict__ We1,
                           const float* __restrict__ We2, const float* __restrict__ We3,
                           const float* __restrict__ Wwvec, const float* __restrict__ Ww,
                           const float* __restrict__ Wm0, const float* __restrict__ Wm1,
                           const float* __restrict__ Wm2, const float* __restrict__ WV,
                           const float* __restrict__ Wr0, const float* __restrict__ Wrout,
                           unsigned short* __restrict__ WT, float* __restrict__ vr,
                           int* __restrict__ cursor,
                           float* __restrict__ out, const int* __restrict__ species,
                           const float* __restrict__ pe) {
  const int b = blockIdx.x, t = threadIdx.x;
  if (b >= 15) {
    int i = (b - 15) * 256 + t;
    if (i < N_NODES) { out[i] = pe[species[i]]; cursor[i] = 0; cursor[N_NODES + i] = 0; }
    return;
  }
  if (b == 4) {
    unsigned short* d4 = WT + OFF_W0;
    for (int idx = t; idx < 48 * 64; idx += 256) {
      int n = idx >> 6, k = idx & 63;
      float v = (n < 32) ? Ww[k * 32 + n] * 0.125f
                         : ((n == 32) ? Wwvec[k] * 0.125f : 0.f);
      d4[n * 64 + k] = f2b(v);
    }
    return;
  }
  if (b == 14) {
    __shared__ float tmp[64];
    if (t < 64) {
      float s = 0.f;
      for (int j = 0; j < 64; ++j) s += Wr0[t * 64 + j] * Wrout[j];
      tmp[t] = s;
    }
    __syncthreads();
    if (t < 64) {
      const float* Wm2b = Wm2 + 4096;  // l=1 block
      float s2 = 0.f;
      for (int n = 0; n < 64; ++n) s2 += Wm2b[t * 64 + n] * tmp[n];
      vr[t] = s2;
    }
    return;
  }
  const float* src = nullptr; unsigned short* dst = nullptr;
  int KIN = 0, N = 0, KP = 0; float scl = 1.f;
  switch (b) {
    case 0:  src = We0;        dst = WT + OFF_E0;  KIN = 72;  N = 64;  KP = 96;  scl = 0.11785113f; break;
    case 1:  src = We1;        dst = WT + OFF_E1;  KIN = 64;  N = 128; KP = 64;  scl = 0.125f; break;
    case 2:  src = We2;        dst = WT + OFF_E2;  KIN = 128; N = 256; KP = 128; scl = 0.08838835f; break;
    case 3:  src = We3;        dst = WT + OFF_E3;  KIN = 256; N = 64;  KP = 256; scl = 0.0625f; break;
    case 5:  src = Ww + 2048;  dst = WT + OFF_W1;  KIN = 64;  N = 32;  KP = 64;  scl = 0.125f; break;
    case 6:  src = Wm0;        dst = WT + OFF_M00; KIN = 96;  N = 64;  KP = 96;  scl = 0.10206207f; break;
    case 7:  src = Wm0 + 6144; dst = WT + OFF_M01; KIN = 96;  N = 64;  KP = 96;  scl = 0.10206207f; break;
    case 8:  src = Wm1;        dst = WT + OFF_M10; KIN = 64;  N = 64;  KP = 64;  scl = 0.125f; break;
    case 9:  src = Wm1 + 4096; dst = WT + OFF_M11; KIN = 64;  N = 64;  KP = 64;  scl = 0.125f; break;
    case 10: src = Wm2;        dst = WT + OFF_M20; KIN = 64;  N = 64;  KP = 64;  scl = 0.125f; break;
    case 12: src = WV;         dst = WT + OFF_V0;  KIN = 32;  N = 32;  KP = 32;  scl = 0.17677669529663689f; break;
    default: return;
  }
  for (int idx = t; idx < N * KP; idx += 256) {
    int n = idx / KP, k = idx - n * KP;
    float v = (k < KIN) ? src[k * N + n] * scl : 0.f;
    dst[n * KP + k] = f2b(v);
  }
}

// -------------------- gather: 32 lanes/node; 2-edge pipelined bucket walk ------
__global__ __launch_bounds__(256) void kgather(const int* __restrict__ cursor,
                                               const int* __restrict__ bucket,
                                               const unsigned short* __restrict__ wg,
                                               const float* __restrict__ yg,
                                               unsigned short* __restrict__ nwY) {
  const int n = blockIdx.x * 8 + (threadIdx.x >> 5);
  const int c = threadIdx.x & 31;
  const int cnt = cursor[n];
  const int* bk = bucket + (size_t)n * CAP;
  float a0 = 0.f, a1 = 0.f, a2 = 0.f, a3 = 0.f;
  int ea = (cnt > 0) ? __builtin_amdgcn_readfirstlane(bk[0]) : 0;
  int eb = (cnt > 1) ? __builtin_amdgcn_readfirstlane(bk[1]) : 0;
  int i = 0;
  for (; i + 2 <= cnt; i += 2) {
    int ec = (i + 2 < cnt) ? __builtin_amdgcn_readfirstlane(bk[i + 2]) : 0;
    int ed = (i + 3 < cnt) ? __builtin_amdgcn_readfirstlane(bk[i + 3]) : 0;
    float wa = b2f(wg[(size_t)ea * 32 + c]);
    float4 ya = ((const float4*)yg)[ea];
    float wb = b2f(wg[(size_t)eb * 32 + c]);
    float4 yb = ((const float4*)yg)[eb];
    a0 += wa + wb;
    a1 = fmaf(wa, ya.x, fmaf(wb, yb.x, a1));
    a2 = fmaf(wa, ya.y, fmaf(wb, yb.y, a2));
    a3 = fmaf(wa, ya.z, fmaf(wb, yb.z, a3));
    ea = ec; eb = ed;
  }
  if (i < cnt) {
    float wa = b2f(wg[(size_t)ea * 32 + c]);
    float4 ya = ((const float4*)yg)[ea];
    a0 += wa;
    a1 = fmaf(wa, ya.x, a1);
    a2 = fmaf(wa, ya.y, a2);
    a3 = fmaf(wa, ya.z, a3);
  }
  *(uint2*)(nwY + (size_t)n * 128 + c * 4) = pack4(a0, a1, a2, a3);
}

#define LDA1 104   // 96 staging cols + pad; x2 never materialized (two-half E1)
#define LDA2 104
#define EPB 128    // edges per block
#define SCR 64     // E2 chunk scratch base col in k1

// -------------------- K1: edge MLP (MT=4; fills bucket inline) ----------
__global__ __launch_bounds__(128, 1) void k1_edge(
    const float* __restrict__ vectors, const int* __restrict__ senders,
    const int* __restrict__ receivers, const int* __restrict__ species,
    const float* __restrict__ emb, const unsigned short* __restrict__ WT,
    unsigned short* __restrict__ xg, float* __restrict__ wvg,
    unsigned short* __restrict__ wg, float* __restrict__ yg,
    int* __restrict__ cursor, int* __restrict__ bucket) {
  __shared__ __align__(16) unsigned short bufA[EPB * LDA1];
  __shared__ float sEnv[EPB];
  const int t = threadIdx.x;
  const int lane = t & 63;
  const int w = t >> 6;
  const int l15 = lane & 15;
  const int q = lane >> 4;
  const int kb = q * 8;
  const int e0 = blockIdx.x * EPB;
  const int row = t;                 // 1 lane per edge
  const int eg = e0 + row;

  // staging: 1 lane per edge (cols 0..95) + inline bucket fill
  {
    float vx = vectors[3 * eg], vy = vectors[3 * eg + 1], vz = vectors[3 * eg + 2];
    float dd = fmaxf(sqrtf(vx * vx + vy * vy + vz * vz), 1e-6f);
    float d2 = dd * dd, d6 = d2 * d2 * d2;
    float env = (dd < 1.f) ? (1.f + d6 * (-28.f + 48.f * dd - 21.f * d2)) : 0.f;
    float inv_d = 1.f / dd;
    {
      const float SQ3 = 1.7320508075688772f;
      float4 yv;
      yv.x = SQ3 * vx * inv_d; yv.y = SQ3 * vy * inv_d; yv.z = SQ3 * vz * inv_d;
      yv.w = env;
      ((float4*)yg)[eg] = yv;
      sEnv[row] = env;
    }
    float c = 1.4142135623730951f * env * inv_d;
    const float PI_F = 3.14159265358979323846f;
#pragma unroll
    for (int n = 0; n < 4; ++n) {
      float s0 = c * __sinf((float)(n + 1) * PI_F * dd);
      float s1 = c * __sinf((float)(n + 5) * PI_F * dd);
      bufA[row * LDA1 + n] = f2b(s0);
      bufA[row * LDA1 + n + 4] = f2b(s1);
    }
    int snd = senders[eg];
    int pos = atomicAdd(&cursor[snd], 1);
    bucket[(size_t)snd * CAP + pos] = eg;
    int ss = species[snd];
    int sr = species[receivers[eg]];
    const float4* es = (const float4*)(emb + ss * 32);
    const float4* er = (const float4*)(emb + sr * 32);
#pragma unroll
    for (int it = 0; it < 8; ++it) {
      float4 zs = es[it];
      float4 zr = er[it];
      uint2 ps, pr;
      ps.x = (unsigned)f2b(zs.x) | ((unsigned)f2b(zs.y) << 16);
      ps.y = (unsigned)f2b(zs.z) | ((unsigned)f2b(zs.w) << 16);
      pr.x = (unsigned)f2b(zr.x) | ((unsigned)f2b(zr.y) << 16);
      pr.y = (unsigned)f2b(zr.z) | ((unsigned)f2b(zr.w) << 16);
      *(uint2*)(bufA + row * LDA1 + 8 + it * 4) = ps;
      *(uint2*)(bufA + row * LDA1 + 40 + it * 4) = pr;
    }
    uint4 zz = {0, 0, 0, 0};
    *(uint4*)(bufA + row * LDA1 + 72) = zz;
    *(uint4*)(bufA + row * LDA1 + 80) = zz;
    *(uint4*)(bufA + row * LDA1 + 88) = zz;
  }

  wave_layer<4, 96, 64, true, false, LDA1, LDA1>(WT + OFF_E0, bufA, bufA, nullptr);

  // E1 (64->128, silu) in two half-passes: input pre-read into b1 regs.
  s16x8 b1[4][2];
#pragma unroll
  for (int m = 0; m < 4; ++m)
#pragma unroll
    for (int kt = 0; kt < 2; ++kt)
      b1[m][kt] = ld_frag(bufA + (w * 64 + m * 16 + l15) * LDA1 + kt * 32 + kb);
  s16x8 a2[4][4];
#pragma unroll
  for (int half = 0; half < 2; ++half) {
    const unsigned short* WTh = WT + OFF_E1 + half * (64 * 64);
#pragma unroll
    for (int nt = 0; nt < 4; ++nt) {
      const unsigned short* wp = WTh + (nt * 16 + l15) * 64 + kb;
      s16x8 wf0 = ld_frag(wp);
      s16x8 wf1 = ld_frag(wp + 32);
      __builtin_amdgcn_s_setprio(1);
#pragma unroll
      for (int m = 0; m < 4; ++m) {
        f32x4 acc = {0.f, 0.f, 0.f, 0.f};
        acc = __builtin_amdgcn_mfma_f32_16x16x32_bf16(wf0, b1[m][0], acc, 0, 0, 0);
        acc = __builtin_amdgcn_mfma_f32_16x16x32_bf16(wf1, b1[m][1], acc, 0, 0, 0);
        const int rr = w * 64 + m * 16 + l15;
        *(uint2*)(bufA + rr * LDA1 + nt * 16 + q * 4) =
            pack4(silu_f(acc[0]), silu_f(acc[1]), silu_f(acc[2]), silu_f(acc[3]));
      }
      __builtin_amdgcn_s_setprio(0);
    }
#pragma unroll
    for (int m = 0; m < 4; ++m)
#pragma unroll
      for (int kt = 0; kt < 2; ++kt)
        a2[m][half * 2 + kt] =
            ld_frag(bufA + (w * 64 + m * 16 + l15) * LDA1 + kt * 32 + kb);
  }

  // fused E2 (128->256, silu) + E3 (256->64), MT=4; scratch cols 64..95.
  // unroll 2: chunk cc+1's weight loads overlap cc's E3 tail.
  f32x4 acc3[4][4];
#pragma unroll
  for (int m = 0; m < 4; ++m)
#pragma unroll
    for (int nt = 0; nt < 4; ++nt) acc3[m][nt] = (f32x4){0.f, 0.f, 0.f, 0.f};
#pragma unroll 2
  for (int cc = 0; cc < 8; ++cc) {
    s16x8 e3wf[4];
#pragma unroll
    for (int nt = 0; nt < 4; ++nt)
      e3wf[nt] = ld_frag(WT + OFF_E3 + (nt * 16 + l15) * 256 + cc * 32 + kb);
#pragma unroll
    for (int nt = 0; nt < 2; ++nt) {
      const unsigned short* wp = WT + OFF_E2 + ((cc * 2 + nt) * 16 + l15) * 128 + kb;
      f32x4 acc[4];
#pragma unroll
      for (int m = 0; m < 4; ++m) acc[m] = (f32x4){0.f, 0.f, 0.f, 0.f};
      __builtin_amdgcn_s_setprio(1);
#pragma unroll
      for (int kt = 0; kt < 4; ++kt) {
        s16x8 wf = ld_frag(wp + kt * 32);
#pragma unroll
        for (int m = 0; m < 4; ++m)
          acc[m] = __builtin_amdgcn_mfma_f32_16x16x32_bf16(wf, a2[m][kt], acc[m], 0, 0, 0);
      }
      __builtin_amdgcn_s_setprio(0);
#pragma unroll
      for (int m = 0; m < 4; ++m) {
        const int rr = w * 64 + m * 16 + l15;
        *(uint2*)(bufA + rr * LDA1 + SCR + nt * 16 + q * 4) =
            pack4(silu_f(acc[m][0]), silu_f(acc[m][1]), silu_f(acc[m][2]), silu_f(acc[m][3]));
      }
    }
    __builtin_amdgcn_s_setprio(1);
#pragma unroll
    for (int m = 0; m < 4; ++m) {
      s16x8 aa = ld_frag(bufA + (w * 64 + m * 16 + l15) * LDA1 + SCR + kb);
#pragma unroll
      for (int nt = 0; nt < 4; ++nt)
        acc3[m][nt] = __builtin_amdgcn_mfma_f32_16x16x32_bf16(e3wf[nt], aa, acc3[m][nt], 0, 0, 0);
    }
    __builtin_amdgcn_s_setprio(0);
  }
  // epilogue: x = env * x3 -> bufA cols 0..63
#pragma unroll
  for (int m = 0; m < 4; ++m) {
    const int rr = w * 64 + m * 16 + l15;
    const float env = sEnv[rr];
#pragma unroll
    for (int nt = 0; nt < 4; ++nt)
      *(uint2*)(bufA + rr * LDA1 + nt * 16 + q * 4) =
          pack4(acc3[m][nt][0] * env, acc3[m][nt][1] * env,
                acc3[m][nt][2] * env, acc3[m][nt][3] * env);
  }
  // vectorized copy own rows -> xg (wave w: rows w*64..w*64+63)
#pragma unroll
  for (int it = 0; it < 8; ++it) {
    int idx = it * 64 + lane;
    int e_l = w * 64 + (idx >> 3), ch = idx & 7;
    *(uint4*)(xg + (size_t)(e0 + e_l) * 64 + ch * 8) =
        *(const uint4*)(bufA + e_l * LDA1 + ch * 8);
  }
  w_store<true, 4, LDA1>(WT + OFF_W0, bufA, wg, wvg, e0);
}

// -------------------- K2: layer l=0 (MT=4; staging-first; bf16 nwY) ----------
__global__ __launch_bounds__(128, 1) void k2_layer0(
    const int* __restrict__ senders, const float* __restrict__ Wvinit,
    const unsigned short* __restrict__ WT, unsigned short* __restrict__ xg,
    const float* __restrict__ wvg, unsigned short* __restrict__ h1g,
    const unsigned short* __restrict__ nwY0, unsigned short* __restrict__ wg,
    const float* __restrict__ yg, const float* __restrict__ vepsp) {
  __shared__ __align__(16) unsigned short bufA[EPB * LDA2];
  __shared__ float sEnv[EPB];
  const int t = threadIdx.x;
  const int lane = t & 63;
  const int w = t >> 6;
  const int l15 = lane & 15;
  const int q = lane >> 4;
  const int kb = q * 8;
  const int e0 = blockIdx.x * EPB;
  const float eps = rsqrtf(1.f + log1pf(__expf(vepsp[0])));

  // (a) stage sout (cols 64..95) + hcb (cols 0..31); 1 lane per edge
  {
    const int row = t;
    const int ee = e0 + row;
    int snd = senders[ee];
    float4 y = ((const float4*)yg)[ee];
    float wvc = wvg[ee] * (1.f / 66.f);
    sEnv[row] = y.w;
    const unsigned short* nwp = nwY0 + (size_t)snd * 128;
    const float IS3 = 0.57735026918962576f;
#pragma unroll 4
    for (int j = 0; j < 16; ++j) {
      int c = 2 * j;
      U16x8 nw; nw.u = *(const uint4*)(nwp + c * 4);
      float h0a = wvc * Wvinit[c];
      float h0b = wvc * Wvinit[c + 1];
      float ska = b2f((unsigned short)nw.s[1]) * y.x + b2f((unsigned short)nw.s[2]) * y.y
                + b2f((unsigned short)nw.s[3]) * y.z;
      float skb = b2f((unsigned short)nw.s[5]) * y.x + b2f((unsigned short)nw.s[6]) * y.y
                + b2f((unsigned short)nw.s[7]) * y.z;
      unsigned pa = (unsigned)f2b(h0a * eps * ska * IS3) |
                    ((unsigned)f2b(h0b * eps * skb * IS3) << 16);
      *(unsigned*)(bufA + row * LDA2 + 64 + c) = pa;
      unsigned pb = (unsigned)f2b(eps * b2f((unsigned short)nw.s[0]) * h0a) |
                    ((unsigned)f2b(eps * b2f((unsigned short)nw.s[4]) * h0b) << 16);
      *(unsigned*)(bufA + row * LDA2 + c) = pb;
    }
  }
  // (b) V-layer (32x32, swapped) reads hcb from cols 0..31 -> h1g
  __builtin_amdgcn_s_setprio(1);
#pragma unroll
  for (int m = 0; m < 4; ++m) {
    const int rr = w * 64 + m * 16 + l15;
    s16x8 b0 = ld_frag(bufA + rr * LDA2 + kb);
#pragma unroll
    for (int nt = 0; nt < 2; ++nt) {
      f32x4 acc = {0.f, 0.f, 0.f, 0.f};
      acc = __builtin_amdgcn_mfma_f32_16x16x32_bf16(
          ld_frag(WT + OFF_V0 + (nt * 16 + l15) * 32 + kb), b0, acc, 0, 0, 0);
      *(uint2*)(h1g + (size_t)(e0 + rr) * 32 + nt * 16 + q * 4) =
          pack4(acc[0], acc[1], acc[2], acc[3]);
    }
  }
  __builtin_amdgcn_s_setprio(0);
  // (c) load x into cols 0..63 (overwrites hcb; same-wave ordering keeps it safe)
#pragma unroll
  for (int it = 0; it < 8; ++it) {
    int idx = it * 64 + lane;
    int e_l = w * 64 + (idx >> 3), ch = idx & 7;
    *(uint4*)(bufA + e_l * LDA2 + ch * 8) =
        *(const uint4*)(xg + (size_t)(e0 + e_l) * 64 + ch * 8);
  }
  wave_layer<4, 96, 64, true, false, LDA2, LDA2>(WT + OFF_M00, bufA, bufA, nullptr);
  wave_layer<4, 64, 64, true, false, LDA2, LDA2>(WT + OFF_M10, bufA, bufA, nullptr);
  wave_layer<4, 64, 64, false, true, LDA2, LDA2>(WT + OFF_M20, bufA, bufA, sEnv);
#pragma unroll
  for (int it = 0; it < 8; ++it) {
    int idx = it * 64 + lane;
    int e_l = w * 64 + (idx >> 3), ch = idx & 7;
    *(uint4*)(xg + (size_t)(e0 + e_l) * 64 + ch * 8) =
        *(const uint4*)(bufA + e_l * LDA2 + ch * 8);
  }
  w_store<false, 4, LDA2>(WT + OFF_W1, bufA, wg, nullptr, e0);
}

// -------------------- K3: layer l=1 + readout (MT=4; staging-first) ------------
__global__ __launch_bounds__(128, 1) void k3_layer1(
    const int* __restrict__ senders, const int* __restrict__ receivers,
    const unsigned short* __restrict__ WT, const float* __restrict__ vr,
    const unsigned short* __restrict__ xg, const unsigned short* __restrict__ h1g,
    const unsigned short* __restrict__ nwY1, const float* __restrict__ yg,
    float* __restrict__ out, const float* __restrict__ vepsp) {
  __shared__ __align__(16) unsigned short bufA[EPB * LDA2];
  __shared__ float sEnv[EPB];
  const int t = threadIdx.x;
  const int lane = t & 63;
  const int w = t >> 6;
  const int e0 = blockIdx.x * EPB;
  const float eps = rsqrtf(1.f + log1pf(__expf(vepsp[0])));

  // (a) random-latency staging FIRST (nwY1 + h1g) -> cols 64..95
  {
    const int row = t;
    const int ee = e0 + row;
    int snd = senders[ee];
    float4 y = ((const float4*)yg)[ee];
    sEnv[row] = y.w;
    const unsigned short* nwp = nwY1 + (size_t)snd * 128;
    U16x8 hv[4];
#pragma unroll
    for (int h = 0; h < 4; ++h)
      hv[h].u = *(const uint4*)(h1g + (size_t)ee * 32 + h * 8);
    const float IS3 = 0.57735026918962576f;
#pragma unroll 4
    for (int j = 0; j < 16; ++j) {
      int c = 2 * j;
      U16x8 nw; nw.u = *(const uint4*)(nwp + c * 4);
      float hca = b2f((unsigned short)hv[c >> 3].s[c & 7]);
      float hcb2 = b2f((unsigned short)hv[(c + 1) >> 3].s[(c + 1) & 7]);
      float ska = b2f((unsigned short)nw.s[1]) * y.x + b2f((unsigned short)nw.s[2]) * y.y
                + b2f((unsigned short)nw.s[3]) * y.z;
      float skb = b2f((unsigned short)nw.s[5]) * y.x + b2f((unsigned short)nw.s[6]) * y.y
                + b2f((unsigned short)nw.s[7]) * y.z;
      unsigned pa = (unsigned)f2b(hca * eps * ska * IS3) |
                    ((unsigned)f2b(hcb2 * eps * skb * IS3) << 16);
      *(unsigned*)(bufA + row * LDA2 + 64 + c) = pa;
    }
  }
  // (b) sequential x-load -> cols 0..63 (disjoint cols, same wave rows)
#pragma unroll
  for (int it = 0; it < 8; ++it) {
    int idx = it * 64 + lane;
    int e_l = w * 64 + (idx >> 3), ch = idx & 7;
    *(uint4*)(bufA + e_l * LDA2 + ch * 8) =
        *(const uint4*)(xg + (size_t)(e0 + e_l) * 64 + ch * 8);
  }
  wave_layer<4, 96, 64, true, false, LDA2, LDA2>(WT + OFF_M01, bufA, bufA, nullptr);
  wave_layer<4, 64, 64, true, false, LDA2, LDA2>(WT + OFF_M11, bufA, bufA, nullptr);
  // readout on M11 output (M21 + Wr0 + Wrout collapsed into vr2)
  {
    const int row = t;
    float dot = 0.f;
#pragma unroll
    for (int h = 0; h < 8; ++h) {
      U16x8 xv; xv.u = *(const uint4*)(bufA + row * LDA2 + h * 8);
#pragma unroll
      for (int j = 0; j < 8; ++j)
        dot = fmaf(b2f((unsigned short)xv.s[j]), vr[h * 8 + j], dot);
    }
    float env = sEnv[row];
    int rcv = receivers[e0 + row];
    atomAddF(out + rcv, dot * 0.001953125f * env * env);
  }
}

// -------------------- launch --------------------
extern "C" void kernel_launch(void* const* d_in, const int* in_sizes, int n_in,
                              void* d_out, int out_size, void* d_ws, size_t ws_size,
                              hipStream_t stream) {
  const float* vectors   = (const float*)d_in[0];
  const int*   senders   = (const int*)d_in[1];
  const int*   receivers = (const int*)d_in[2];
  const int*   species   = (const int*)d_in[3];
  const float* emb       = (const float*)d_in[4];
  const float* We0       = (const float*)d_in[5];
  const float* We1       = (const float*)d_in[6];
  const float* We2       = (const float*)d_in[7];
  const float* We3       = (const float*)d_in[8];
  const float* Wwvec     = (const float*)d_in[9];
  const float* Wvinit    = (const float*)d_in[10];
  const float* Ww        = (const float*)d_in[11];
  const float* Wm0       = (const float*)d_in[12];
  const float* Wm1       = (const float*)d_in[13];
  const float* Wm2       = (const float*)d_in[14];
  const float* WV        = (const float*)d_in[15];
  const float* Wr0       = (const float*)d_in[16];
  const float* Wrout     = (const float*)d_in[17];
  const float* pe        = (const float*)d_in[18];
  const float* veps      = (const float*)d_in[19];
  float* outp = (float*)d_out;

  unsigned short* wsu = (unsigned short*)d_ws;
  unsigned short* WT  = wsu;
  float* vr           = (float*)(wsu + WT_END);
  unsigned short* xg  = wsu + WT_END + 128;                   // E*64 bf16
  unsigned short* h1g = xg + (size_t)E_EDGES * 64;            // E*32 bf16
  unsigned short* wg  = h1g + (size_t)E_EDGES * 32;           // E*32 bf16
  float* wvg          = (float*)(wg + (size_t)E_EDGES * 32);  // E f32
  float* yg           = wvg + E_EDGES;                        // E*4 f32 (Y1,env)
  unsigned short* nwY0 = (unsigned short*)(yg + (size_t)E_EDGES * 4); // N*128 bf16
  unsigned short* nwY1 = nwY0 + N_NODES * 128;                // N*128 bf16
  int* cursor         = (int*)(nwY1 + N_NODES * 128);         // 2*N
  int* bucket         = cursor + 2 * N_NODES;                 // N*CAP

  const int nblk = E_EDGES / EPB;  // 2500

  hipLaunchKernelGGL(kprep_init, dim3(15 + (N_NODES + 255) / 256), dim3(256), 0, stream,
                     We0, We1, We2, We3, Wwvec, Ww, Wm0, Wm1, Wm2, WV, Wr0, Wrout,
                     WT, vr, cursor, outp, species, pe);
  hipLaunchKernelGGL(k1_edge, dim3(nblk), dim3(128), 0, stream,
                     vectors, senders, receivers, species, emb, WT, xg, wvg, wg, yg,
                     cursor, bucket);
  hipLaunchKernelGGL(kgather, dim3(N_NODES / 8), dim3(256), 0, stream,
                     cursor, bucket, wg, yg, nwY0);
  hipLaunchKernelGGL(k2_layer0, dim3(nblk), dim3(128), 0, stream,
                     senders, Wvinit, WT, xg, wvg, h1g, nwY0, wg, yg, veps);
  hipLaunchKernelGGL(kgather, dim3(N_NODES / 8), dim3(256), 0, stream,
                     cursor, bucket, wg, yg, nwY1);
  hipLaunchKernelGGL(k3_layer1, dim3(nblk), dim3(128), 0, stream,
                     senders, receivers, WT, vr, xg, h1g, nwY1, yg, outp, veps);
}